// Round 1
// 1443.093 us; speedup vs baseline: 1.1579x; 1.1579x over previous
//
#include <hip/hip_runtime.h>
#include <stdint.h>

// Binary-weight MLP forward, exact int8 digit-plane formulation.
// R4: gemm_direct restructured as a 3-stage global_load_lds pipeline with
// counted s_waitcnt vmcnt(6) (never 0 in the main loop) + raw s_barrier.
// Both A (digit planes) and B (signs) stream through LDS; no A-register
// staging (frees ~50 VGPRs), 2 full stages of latency cover (~1170 cyc).

typedef int v4i  __attribute__((ext_vector_type(4)));
typedef int v16i __attribute__((ext_vector_type(16)));

#define B_ROWS   16384
#define DIM      4096
#define MT       64      // block m-tile
#define NT       128     // block n-tile
#define KT       64      // k-tile (pipeline stage)

#define WS_LOGIT  0
#define WS_W2S    65536
#define WS_B      69632
#define WS_A      (69632 + 16777216)
#define WS_NEEDED ((size_t)WS_A + 268435456ULL)

__device__ __forceinline__ void dma16(const void* g, void* l) {
    __builtin_amdgcn_global_load_lds(
        (const __attribute__((address_space(1))) void*)g,
        (__attribute__((address_space(3))) void*)l, 16, 0, 0);
}

// ---------------- pack x -> fragment-ordered digit planes in wsA -----------
// Global layout: offA(m,k,d) = (m>>5)<<19 | (k>>5)<<12 | d<<10 | L<<4 | (k&15)
//   with L = ((k>>4)&1)*32 + (m&31)  (== MFMA A-operand lane index).
__global__ void pack_x_frag_kernel(const float* __restrict__ x, int8_t* __restrict__ wsA) {
    __shared__ __align__(16) int8_t tile[16384];
    const int mb32 = blockIdx.x, t = threadIdx.x;
    const int r = t >> 3;          // row within 32-row group
    const int c = t & 7;           // float4-column subgroup
    const int kh = (c >> 2) & 1;   // (k>>4)&1 for this thread's elements
    const int L = kh * 32 + r;
    const int ldsQ = L * 16 + (c & 3) * 4;   // + i*4096 + d*1024
    const float* srcRow = x + ((size_t)(mb32 * 32 + r) << 12);
    int8_t* dstBase = wsA + ((size_t)mb32 << 19);

    for (int kw = 0; kw < 32; ++kw) {
#pragma unroll
        for (int i = 0; i < 4; ++i) {
            const int j = c + 8 * i;                       // float4 index in window
            float4 f = ((const float4*)(srcRow + (kw << 7)))[j];
            float fv[4] = {f.x, f.y, f.z, f.w};
            int dig[4][4];                                  // [elem][digit]
#pragma unroll
            for (int e = 0; e < 4; ++e) {
                int v = __float2int_rn(fv[e] * 67108864.0f); // * 2^26, exact
#pragma unroll
                for (int d = 0; d < 4; ++d) {
                    int b = (int)(int8_t)(v & 0xff);
                    dig[e][d] = b & 0xff;
                    v = (v - b) >> 8;                        // exact
                }
            }
#pragma unroll
            for (int d = 0; d < 4; ++d) {
                uint32_t wrd = (uint32_t)dig[0][d] | ((uint32_t)dig[1][d] << 8)
                             | ((uint32_t)dig[2][d] << 16) | ((uint32_t)dig[3][d] << 24);
                *(uint32_t*)(tile + i * 4096 + d * 1024 + ldsQ) = wrd;
            }
        }
        __syncthreads();
        {   // tile is byte-identical to global span [mb32<<19 | kw<<14 .. +16KB)
            const int4* s = (const int4*)tile;
            int4* dst = (int4*)(dstBase + ((size_t)kw << 14));
#pragma unroll
            for (int q = 0; q < 4; ++q) dst[t + 256 * q] = s[t + 256 * q];
        }
        __syncthreads();
    }
}

// ---------------- fallback: R1 planar in-place pack ------------------------
__global__ void pack_x_kernel(float* __restrict__ x) {
    const int b = blockIdx.x, t = threadIdx.x;
    float* row = x + (size_t)b * DIM;
    float f[16];
#pragma unroll
    for (int i = 0; i < 4; ++i) {
        float4 v = ((const float4*)(row + t * 16))[i];
        f[i*4+0] = v.x; f[i*4+1] = v.y; f[i*4+2] = v.z; f[i*4+3] = v.w;
    }
    __syncthreads();
    uint32_t wds[4][4];
#pragma unroll
    for (int j = 0; j < 4; ++j) {
#pragma unroll
        for (int d = 0; d < 4; ++d) wds[d][j] = 0u;
#pragma unroll
        for (int i = 0; i < 4; ++i) {
            int v = __float2int_rn(f[j*4+i] * 67108864.0f);
#pragma unroll
            for (int d = 0; d < 4; ++d) {
                int bb = (int)(int8_t)(v & 0xff);
                wds[d][j] |= (uint32_t)(bb & 0xff) << (8 * i);
                v = (v - bb) >> 8;
            }
        }
    }
    int8_t* rowb = (int8_t*)row;
#pragma unroll
    for (int d = 0; d < 4; ++d) {
        int4 o; o.x = (int)wds[d][0]; o.y = (int)wds[d][1];
        o.z = (int)wds[d][2]; o.w = (int)wds[d][3];
        *(int4*)(rowb + d * DIM + t * 16) = o;
    }
}

// ---------------- pack W1 signs into MFMA-fragment-ordered blocks ----------
__global__ void pack_w1_kernel(const float* __restrict__ W1, int8_t* __restrict__ wsB) {
    const int tg = blockIdx.x * 256 + threadIdx.x;
    const int n  = tg >> 8;
    const int k0 = (tg & 255) << 4;
    const float* src = W1 + (size_t)n * DIM + k0;
    uint32_t w[4];
#pragma unroll
    for (int j = 0; j < 4; ++j) {
        float4 v = ((const float4*)src)[j];
        uint32_t b0 = (v.x >= 0.f) ? 0x01u : 0xFFu;
        uint32_t b1 = (v.y >= 0.f) ? 0x01u : 0xFFu;
        uint32_t b2 = (v.z >= 0.f) ? 0x01u : 0xFFu;
        uint32_t b3 = (v.w >= 0.f) ? 0x01u : 0xFFu;
        w[j] = b0 | (b1 << 8) | (b2 << 16) | (b3 << 24);
    }
    const int nb = n >> 7, kt = k0 >> 6;
    const int nsub = (n >> 5) & 3, ks = (k0 >> 5) & 1;
    const int L = (n & 31) | (((k0 >> 4) & 1) << 5);
    const size_t off = ((size_t)(nb * 64 + kt) << 13) + (nsub << 11) + (ks << 10) + (L << 4);
    int4 o; o.x = (int)w[0]; o.y = (int)w[1]; o.z = (int)w[2]; o.w = (int)w[3];
    *(int4*)(wsB + off) = o;
}

__global__ void pack_w2_kernel(const float* __restrict__ W2, int8_t* __restrict__ w2s) {
    const int j = blockIdx.x * 256 + threadIdx.x;
    if (j < DIM) w2s[j] = (W2[j] >= 0.f) ? (int8_t)1 : (int8_t)-1;
}

// ---------------- R4 GEMM: 3-stage LDS pipeline, counted vmcnt -------------
// Per stage (KT=64) per wave: 6 dma16 (A: 4x1KB one (wyc,ks) group, B: 2x1KB
// one nsub), 12 ds_read_b128, 16 MFMA. Steady state keeps 2 stages (12 loads)
// in flight; the barrier waits vmcnt(6), never 0, so prefetch spans barriers.
#define STGB 24576

#define PIPE_BARRIER(N) do {                                               \
    __builtin_amdgcn_sched_barrier(0);                                     \
    asm volatile("s_waitcnt vmcnt(" #N ") lgkmcnt(0)" ::: "memory");       \
    __builtin_amdgcn_s_barrier();                                          \
    __builtin_amdgcn_sched_barrier(0);                                     \
} while (0)

// LDS stage layout: A chunk (wyc,ks,d) at ((wyc<<3)|(ks<<2)|d)<<10 (16KB),
// B chunk (nsub,ks) at 16384 + ((nsub<<1)|ks)<<10 (8KB). All chunks are
// 64 lanes x 16B, byte-identical to the global fragment stream -> dma16-able.
#define ISSUE_STAGE(kt_, ib) do {                                          \
    const int8_t* _ga = gA + ((size_t)(kt_) << 13);                        \
    const int8_t* _gb = gB + ((size_t)(kt_) << 13);                        \
    int8_t* _ad = &stg[ib][w << 12];                                       \
    int8_t* _bd = &stg[ib][16384 + (w << 11)];                             \
    dma16(_ga,        _ad);                                                \
    dma16(_ga + 1024, _ad + 1024);                                         \
    dma16(_ga + 2048, _ad + 2048);                                         \
    dma16(_ga + 3072, _ad + 3072);                                         \
    dma16(_gb,        _bd);                                                \
    dma16(_gb + 1024, _bd + 1024);                                         \
} while (0)

#define MFMA_STAGE(cb) do {                                                \
    const int8_t* _ab = &stg[cb][(wy << 13) + (lane << 4)];                \
    const int8_t* _bb = &stg[cb][16384 + (wx << 12) + (lane << 4)];        \
    v4i _af[2][4], _bf[2][2];                                              \
    _Pragma("unroll") for (int _s = 0; _s < 2; ++_s) {                     \
        _Pragma("unroll") for (int _d = 0; _d < 4; ++_d)                   \
            _af[_s][_d] = *(const v4i*)(_ab + (_s << 12) + (_d << 10));    \
        _Pragma("unroll") for (int _n = 0; _n < 2; ++_n)                   \
            _bf[_s][_n] = *(const v4i*)(_bb + (_n << 11) + (_s << 10));    \
    }                                                                      \
    _Pragma("unroll") for (int _s = 0; _s < 2; ++_s)                       \
    _Pragma("unroll") for (int _n = 0; _n < 2; ++_n)                       \
    _Pragma("unroll") for (int _d = 0; _d < 4; ++_d)                       \
        acc[_n][_d] = __builtin_amdgcn_mfma_i32_32x32x32_i8(               \
            _af[_s][_d], _bf[_s][_n], acc[_n][_d], 0, 0, 0);               \
} while (0)

#define STEP(kt_, cb, ib) do {                                             \
    PIPE_BARRIER(6);                                                       \
    ISSUE_STAGE((kt_) + 2, ib);                                            \
    MFMA_STAGE(cb);                                                        \
} while (0)

__launch_bounds__(256, 2)
__global__ void gemm_direct_kernel(const int8_t* __restrict__ wsA,
                                   const int8_t* __restrict__ wsB,
                                   const int8_t* __restrict__ w2s,
                                   int* __restrict__ logit) {
    __shared__ __align__(16) int8_t stg[3][STGB];   // 72 KB, 2 blocks/CU = 144 KB

    const int bid = blockIdx.x;
    const int nb = bid & 31, mb = bid >> 5;   // nb fastest: A window shared in L2
    const int t = threadIdx.x, lane = t & 63, w = t >> 6;
    const int wy = w >> 1, wx = w & 1;        // wave tile: 32(m) x 64(n)

    v16i acc[2][4];
#pragma unroll
    for (int n = 0; n < 2; ++n)
#pragma unroll
        for (int d = 0; d < 4; ++d)
#pragma unroll
            for (int i = 0; i < 16; ++i) acc[n][d][i] = 0;

    // per-wave global chunk bases (per-lane address; LDS dest is wave-uniform)
    // wave w stages A group (wyc=w>>1, ks=w&1, d=0..3) and B group (nsub=w, ks=0..1)
    const int8_t* gA = wsA + ((size_t)(mb * 2 + (w >> 1)) << 19) + ((w & 1) << 12) + (lane << 4);
    const int8_t* gB = wsB + ((size_t)(nb * 64) << 13) + (w << 11) + (lane << 4);

    ISSUE_STAGE(0, 0);
    ISSUE_STAGE(1, 1);

    // 64 stages; consume kt%3, issue (kt+2)%3 (reuse distance 1 is safe: the
    // lgkmcnt(0) in PIPE_BARRIER drains each wave's ds_reads before it passes
    // the barrier, and the overwriting DMA issues only after the barrier).
#pragma unroll 1
    for (int kt = 0; kt < 60; kt += 3) {
        STEP(kt,     0, 2);
        STEP(kt + 1, 1, 0);
        STEP(kt + 2, 2, 1);
    }
    STEP(60, 0, 2);   // issues stage 62 -> buf 2
    STEP(61, 1, 0);   // issues stage 63 -> buf 0
    PIPE_BARRIER(6);  // stage 62 landed
    MFMA_STAGE(2);
    PIPE_BARRIER(0);  // stage 63 landed (final drain)
    MFMA_STAGE(0);

    // epilogue: recombine digits -> exact sign -> *sign(W2) -> row sums -> atomic
    const int half = lane >> 5, col = lane & 31;
    int psum[16];
#pragma unroll
    for (int r = 0; r < 16; ++r) psum[r] = 0;
#pragma unroll
    for (int n = 0; n < 2; ++n) {
        const int j = nb * NT + wx * 64 + n * 32 + col;
        const int w2v = (int)w2s[j];
#pragma unroll
        for (int r = 0; r < 16; ++r) {
            long long h = (long long)acc[n][0][r]
                        + ((long long)acc[n][1][r] << 8)
                        + ((long long)acc[n][2][r] << 16)
                        + ((long long)acc[n][3][r] << 24);
            psum[r] += (h >= 0) ? w2v : -w2v;
        }
    }
#pragma unroll
    for (int r = 0; r < 16; ++r) {
#pragma unroll
        for (int m = 1; m <= 16; m <<= 1)
            psum[r] += __shfl_xor(psum[r], m, 64);
    }
    if (col == 0) {
        const int rowBase = mb * MT + wy * 32 + 4 * half;
#pragma unroll
        for (int r = 0; r < 16; ++r)
            atomicAdd(logit + rowBase + (r & 3) + 8 * (r >> 2), psum[r]);
    }
}

// ---------------- fallback: R1 GEMM (A planar through LDS) -----------------
__launch_bounds__(256, 2)
__global__ void gemm_kernel(const int8_t* __restrict__ xq,
                            const int8_t* __restrict__ wsB,
                            const int8_t* __restrict__ w2s,
                            int* __restrict__ logit) {
    __shared__ __align__(16) int8_t aT[4 * MT * KT];
    __shared__ __align__(16) int8_t bT[NT * KT];

    const int bid = blockIdx.x;
    const int nb = bid & 31, mb = bid >> 5;
    const int t = threadIdx.x, lane = t & 63, w = t >> 6;
    const int wy = w >> 1, wx = w & 1;

    v16i acc[2][4];
#pragma unroll
    for (int n = 0; n < 2; ++n)
#pragma unroll
        for (int d = 0; d < 4; ++d)
#pragma unroll
            for (int i = 0; i < 16; ++i) acc[n][d][i] = 0;

    const int8_t* aSrc = xq + (size_t)(mb * MT + lane) * (4 * DIM) + w * DIM;
    const int8_t* bSrc = wsB + ((size_t)(nb * 64) << 13) + t * 32;
    const int aDst = w * (MT * KT) + ((lane >> 5) << 11) + ((lane & 31) << 4);

    for (int kt = 0; kt < DIM / KT; ++kt) {
#pragma unroll
        for (int k16 = 0; k16 < 4; ++k16) {
            v4i v = *(const v4i*)(aSrc + kt * KT + k16 * 16);
            *(v4i*)(aT + aDst + ((k16 >> 1) << 10) + ((k16 & 1) << 9)) = v;
        }
        {
            const v4i* s = (const v4i*)(bSrc + ((size_t)kt << 13));
            *(v4i*)(bT + t * 32)      = s[0];
            *(v4i*)(bT + t * 32 + 16) = s[1];
        }
        __syncthreads();
#pragma unroll
        for (int s = 0; s < 2; ++s) {
            v4i af[4], bf[2];
#pragma unroll
            for (int d = 0; d < 4; ++d)
                af[d] = *(const v4i*)(aT + d * (MT * KT) + (wy << 11) + (s << 10) + (lane << 4));
#pragma unroll
            for (int n = 0; n < 2; ++n)
                bf[n] = *(const v4i*)(bT + ((wx * 2 + n) << 11) + (s << 10) + (lane << 4));
#pragma unroll
            for (int n = 0; n < 2; ++n)
#pragma unroll
                for (int d = 0; d < 4; ++d)
                    acc[n][d] = __builtin_amdgcn_mfma_i32_32x32x32_i8(af[d], bf[n], acc[n][d], 0, 0, 0);
        }
        __syncthreads();
    }

    const int half = lane >> 5, col = lane & 31;
    int psum[16];
#pragma unroll
    for (int r = 0; r < 16; ++r) psum[r] = 0;
#pragma unroll
    for (int n = 0; n < 2; ++n) {
        const int j = nb * NT + wx * 64 + n * 32 + col;
        const int w2v = (int)w2s[j];
#pragma unroll
        for (int r = 0; r < 16; ++r) {
            long long h = (long long)acc[n][0][r]
                        + ((long long)acc[n][1][r] << 8)
                        + ((long long)acc[n][2][r] << 16)
                        + ((long long)acc[n][3][r] << 24);
            psum[r] += (h >= 0) ? w2v : -w2v;
        }
    }
#pragma unroll
    for (int r = 0; r < 16; ++r) {
#pragma unroll
        for (int m = 1; m <= 16; m <<= 1)
            psum[r] += __shfl_xor(psum[r], m, 64);
    }
    if (col == 0) {
        const int rowBase = mb * MT + wy * 32 + 4 * half;
#pragma unroll
        for (int r = 0; r < 16; ++r)
            atomicAdd(logit + rowBase + (r & 3) + 8 * (r >> 2), psum[r]);
    }
}

// ---------------- finalize: sigmoid + threshold ----------------------------
__global__ void finalize_kernel(const int* __restrict__ logit, float* __restrict__ out) {
    const int b = blockIdx.x * 256 + threadIdx.x;
    if (b < B_ROWS) {
        const int l = logit[b];
        out[b]          = 1.f / (1.f + expf(-(float)l));
        out[B_ROWS + b] = (l >= 0) ? 1.f : 0.f;
    }
}

extern "C" void kernel_launch(void* const* d_in, const int* in_sizes, int n_in,
                              void* d_out, int out_size, void* d_ws, size_t ws_size,
                              hipStream_t stream) {
    float*       x   = (float*)d_in[0];
    const float* W1  = (const float*)d_in[1];
    const float* W2  = (const float*)d_in[2];
    float*       out = (float*)d_out;

    int8_t* ws    = (int8_t*)d_ws;
    int*    logit = (int*)(ws + WS_LOGIT);
    int8_t* w2s   = ws + WS_W2S;
    int8_t* wsB   = ws + WS_B;

    hipMemsetAsync(logit, 0, B_ROWS * sizeof(int), stream);
    pack_w1_kernel<<<DIM, 256, 0, stream>>>(W1, wsB);
    pack_w2_kernel<<<16, 256, 0, stream>>>(W2, w2s);

    if (ws_size >= WS_NEEDED) {
        int8_t* wsA = ws + WS_A;
        pack_x_frag_kernel<<<B_ROWS / 32, 256, 0, stream>>>(x, wsA);
        gemm_direct_kernel<<<(B_ROWS / MT) * (DIM / NT), 256, 0, stream>>>(wsA, wsB, w2s, logit);
    } else {
        pack_x_kernel<<<B_ROWS, 256, 0, stream>>>(x);
        gemm_kernel<<<(B_ROWS / MT) * (DIM / NT), 256, 0, stream>>>((const int8_t*)x, wsB, w2s, logit);
    }
    finalize_kernel<<<B_ROWS / 256, 256, 0, stream>>>(logit, out);
}